// Round 6
// baseline (749.364 us; speedup 1.0000x reference)
//
#include <hip/hip_runtime.h>
#include <hip/hip_bf16.h>
#include <math.h>

// ---------------- constants ----------------
#define BB 8192
#define DD 1024
#define HH 4096
#define EE 4
#define NT 136              // row tiles of 128 covering B*k with per-expert pad to 256
#define CAP (NT * 128)      // 17408 packed-row capacity (256-aligned segments)

typedef __attribute__((ext_vector_type(8))) __bf16 bf16x8;
typedef __attribute__((ext_vector_type(4))) float f32x4;

__device__ __forceinline__ unsigned short f2bf(float f) {
    union { float f; unsigned u; } c; c.f = f;
    unsigned u = c.u;
    unsigned r = (u + 0x7FFFu + ((u >> 16) & 1u)) >> 16;
    return (unsigned short)r;
}

__device__ __forceinline__ void load_lds16(const void* g, void* l) {
    __builtin_amdgcn_global_load_lds(
        (const __attribute__((address_space(1))) void*)g,
        (__attribute__((address_space(3))) void*)l, 16, 0, 0);
}

#define BARRIER() do { asm volatile("" ::: "memory"); \
                       __builtin_amdgcn_s_barrier();  \
                       asm volatile("" ::: "memory"); } while (0)

// ---------------- weight transpose + bf16 convert (both weights, one launch) ----
__global__ void k_prep(const float* __restrict__ w1, const float* __restrict__ w2,
                       unsigned short* __restrict__ w1t, unsigned short* __restrict__ w2t,
                       int* __restrict__ cnt, float* __restrict__ psum,
                       int* __restrict__ done) {
    __shared__ unsigned short tileT[64 * 72];   // [c][r], pad 72
    const int tid = threadIdx.x;
    if (blockIdx.x == 0 && blockIdx.y == 0 && blockIdx.z == 0) {
        if (tid < 4) cnt[tid] = 0;
        else if (tid < 8) psum[tid - 4] = 0.f;
        else if (tid == 8) done[0] = 0;
    }
    const int z = blockIdx.z;
    const float* s;
    unsigned short* d;
    int R, C, r0, c0;
    if (z < 4) {
        s = w1 + (size_t)z * DD * HH;  d = w1t + (size_t)z * DD * HH;
        R = DD; C = HH;
        r0 = blockIdx.y * 64; c0 = blockIdx.x * 64;
    } else {
        const int e = z - 4;
        s = w2 + (size_t)e * DD * HH;  d = w2t + (size_t)e * DD * HH;
        R = HH; C = DD;
        const int idx = blockIdx.y * 64 + blockIdx.x;   // 0..1023
        c0 = (idx & 15) * 64; r0 = (idx >> 4) * 64;
    }
    const int cc = (tid & 15) * 4;
#pragma unroll
    for (int it = 0; it < 4; ++it) {
        int rr = (tid >> 4) + it * 16;
        float4 v = *(const float4*)(s + (size_t)(r0 + rr) * C + c0 + cc);
        tileT[(cc + 0) * 72 + rr] = f2bf(v.x);
        tileT[(cc + 1) * 72 + rr] = f2bf(v.y);
        tileT[(cc + 2) * 72 + rr] = f2bf(v.z);
        tileT[(cc + 3) * 72 + rr] = f2bf(v.w);
    }
    __syncthreads();
#pragma unroll
    for (int it = 0; it < 2; ++it) {
        int chunk = tid + it * 256;
        int cl = chunk >> 3, rl = (chunk & 7) * 8;
        uint4 vv = *(const uint4*)&tileT[cl * 72 + rl];
        *(uint4*)(d + (size_t)(c0 + cl) * R + r0 + rl) = vv;
    }
}

// ---------------- gating + fused aux/offsets (segments padded to 256) ----------
__global__ __launch_bounds__(256) void k_gate(
        const float* __restrict__ x, const float* __restrict__ gw,
        const float* __restrict__ gb,
        float* __restrict__ mu, float* __restrict__ rstd,
        int* __restrict__ cnt, float* __restrict__ psum, int* __restrict__ done,
        int* __restrict__ rows_tmp, float* __restrict__ wts_tmp,
        float* __restrict__ probs_out, float* __restrict__ idx_out,
        float* __restrict__ w_out,
        int* __restrict__ aoff, int* __restrict__ tile_e,
        float* __restrict__ aux_out) {
    const int tid = threadIdx.x;
    const int lane = tid & 63, wv = tid >> 6;
    __shared__ int   s_e[64];
    __shared__ float s_w[64];
    __shared__ int   s_pos[64];
    __shared__ int   s_base[4];
    __shared__ float s_ps[4][4];
    __shared__ int   s_last;

    float lp0 = 0.f, lp1 = 0.f, lp2 = 0.f, lp3 = 0.f;

    for (int i = 0; i < 8; ++i) {
        const int rloc = wv * 8 + i;
        const int r = blockIdx.x * 32 + rloc;
        float l0 = 0, l1 = 0, l2 = 0, l3 = 0, s = 0, ss = 0;
#pragma unroll
        for (int k = 0; k < 4; ++k) {
            const int off = k * 256 + lane * 4;
            float4 xv = *(const float4*)(x + (size_t)r * DD + off);
            s  += xv.x + xv.y + xv.z + xv.w;
            ss += xv.x * xv.x + xv.y * xv.y + xv.z * xv.z + xv.w * xv.w;
            float4 g0 = *(const float4*)(gw + 0 * DD + off);
            float4 g1 = *(const float4*)(gw + 1 * DD + off);
            float4 g2 = *(const float4*)(gw + 2 * DD + off);
            float4 g3 = *(const float4*)(gw + 3 * DD + off);
            l0 += xv.x * g0.x + xv.y * g0.y + xv.z * g0.z + xv.w * g0.w;
            l1 += xv.x * g1.x + xv.y * g1.y + xv.z * g1.z + xv.w * g1.w;
            l2 += xv.x * g2.x + xv.y * g2.y + xv.z * g2.z + xv.w * g2.w;
            l3 += xv.x * g3.x + xv.y * g3.y + xv.z * g3.z + xv.w * g3.w;
        }
#pragma unroll
        for (int off = 32; off > 0; off >>= 1) {
            l0 += __shfl_xor(l0, off, 64);
            l1 += __shfl_xor(l1, off, 64);
            l2 += __shfl_xor(l2, off, 64);
            l3 += __shfl_xor(l3, off, 64);
            s  += __shfl_xor(s,  off, 64);
            ss += __shfl_xor(ss, off, 64);
        }
        if (lane == 0) {
            float m = s * (1.0f / DD);
            float var = ss * (1.0f / DD) - m * m;
            mu[r] = m;
            rstd[r] = rsqrtf(var + 1e-5f);
            float lg[4] = { l0 + gb[0], l1 + gb[1], l2 + gb[2], l3 + gb[3] };
            float mx = fmaxf(fmaxf(lg[0], lg[1]), fmaxf(lg[2], lg[3]));
            float p[4], tot = 0.f;
#pragma unroll
            for (int e = 0; e < 4; ++e) { p[e] = __expf(lg[e] - mx); tot += p[e]; }
            float inv = 1.0f / tot;
#pragma unroll
            for (int e = 0; e < 4; ++e) { p[e] *= inv; probs_out[(size_t)r * 4 + e] = p[e]; }
            lp0 += p[0]; lp1 += p[1]; lp2 += p[2]; lp3 += p[3];
            int e0 = 0; float p0 = p[0];
#pragma unroll
            for (int e = 1; e < 4; ++e) if (p[e] > p0) { p0 = p[e]; e0 = e; }
            int e1 = -1; float p1 = -1.f;
#pragma unroll
            for (int e = 0; e < 4; ++e) if (e != e0 && p[e] > p1) { p1 = p[e]; e1 = e; }
            float s2 = 1.0f / (p0 + p1 + 1e-9f);
            float w0 = p0 * s2, w1v = p1 * s2;
            idx_out[r * 2 + 0] = (float)e0;
            idx_out[r * 2 + 1] = (float)e1;
            w_out[r * 2 + 0] = w0;
            w_out[r * 2 + 1] = w1v;
            s_e[rloc * 2 + 0] = e0; s_w[rloc * 2 + 0] = w0;
            s_e[rloc * 2 + 1] = e1; s_w[rloc * 2 + 1] = w1v;
        }
    }
    if (lane == 0) {
        s_ps[wv][0] = lp0; s_ps[wv][1] = lp1; s_ps[wv][2] = lp2; s_ps[wv][3] = lp3;
    }
    __syncthreads();
    if (tid < 4) {
        int c = 0;
        for (int k = 0; k < 64; ++k)
            if (s_e[k] == tid) s_pos[k] = c++;
        s_base[tid] = atomicAdd(cnt + tid, c);
        atomicAdd(psum + tid, s_ps[0][tid] + s_ps[1][tid] + s_ps[2][tid] + s_ps[3][tid]);
    }
    __syncthreads();
    if (tid < 64) {
        int e = s_e[tid];
        int p = s_base[e] + s_pos[tid];
        int r = blockIdx.x * 32 + (tid >> 1);
        rows_tmp[e * BB + p] = r;
        wts_tmp[e * BB + p] = s_w[tid];
    }
    __threadfence();
    __syncthreads();
    if (tid == 0) s_last = atomicAdd(done, 1);
    __syncthreads();
    if (s_last == (int)gridDim.x - 1 && tid == 0) {
        int c[4];
        for (int e = 0; e < 4; ++e) c[e] = atomicAdd(cnt + e, 0);
        float aux = 0.f;
        int a = 0; aoff[0] = 0;
        for (int e = 0; e < 4; ++e) {
            float mean_p = atomicAdd(psum + e, 0.f) * (1.0f / BB);
            aux += ((float)c[e] * (1.0f / (BB * 2))) * mean_p;
            a += ((c[e] + 255) >> 8) << 8; aoff[e + 1] = a;   // 256-aligned segments
        }
        aux_out[0] = 4.0f * aux;
        for (int t = 0; t < NT; ++t) {
            int ee = 0;
            for (int e = 0; e < 4; ++e)
                if (t * 128 >= aoff[e] && t * 128 < aoff[e + 1]) ee = e;
            tile_e[t] = ee;
        }
    }
}

// ---------------- pack: gather rows, LN + affine, bf16; also zeroes y ----------
__global__ __launch_bounds__(256) void k_pack(
        const float* __restrict__ x, const float* __restrict__ lnw,
        const float* __restrict__ lnb,
        const float* __restrict__ mu, const float* __restrict__ rstd,
        const int* __restrict__ cnt, const int* __restrict__ aoff,
        const int* __restrict__ tile_e,
        const int* __restrict__ rows_tmp, const float* __restrict__ wts_tmp,
        int* __restrict__ row_pk, float* __restrict__ wt_pk,
        unsigned short* __restrict__ Apk, float* __restrict__ y) {
    const int blk = blockIdx.x, tid = threadIdx.x;
    const int wv = tid >> 6, lane = tid & 63;
    if (blk < BB / 4) {
        float4 z4; z4.x = z4.y = z4.z = z4.w = 0.f;
        float* yr = y + (size_t)(blk * 4 + wv) * DD + lane * 4;
#pragma unroll
        for (int k = 0; k < 4; ++k) *(float4*)(yr + k * 256) = z4;
    }
    const int i = blk * 4 + wv;
    if (i >= aoff[4]) return;
    const int e = tile_e[i >> 7];
    const int j = i - aoff[e];
    unsigned short* dst = Apk + (size_t)i * DD;
    if (j < cnt[e]) {
        int b = rows_tmp[e * BB + j];
        if (lane == 0) { row_pk[i] = b; wt_pk[i] = wts_tmp[e * BB + j]; }
        float m = mu[b], rs = rstd[b];
#pragma unroll
        for (int k = 0; k < 4; ++k) {
            const int off = k * 256 + lane * 4;
            float4 xv = *(const float4*)(x + (size_t)b * DD + off);
            float4 wv4 = *(const float4*)(lnw + (size_t)e * DD + off);
            float4 bv4 = *(const float4*)(lnb + (size_t)e * DD + off);
            ushort4 o;
            o.x = f2bf((xv.x - m) * rs * wv4.x + bv4.x);
            o.y = f2bf((xv.y - m) * rs * wv4.y + bv4.y);
            o.z = f2bf((xv.z - m) * rs * wv4.z + bv4.z);
            o.w = f2bf((xv.w - m) * rs * wv4.w + bv4.w);
            *(ushort4*)(dst + off) = o;
        }
    } else {
        if (lane == 0) { row_pk[i] = -1; wt_pk[i] = 0.f; }
        ushort4 z; z.x = z.y = z.z = z.w = 0;
#pragma unroll
        for (int k = 0; k < 4; ++k) *(ushort4*)(dst + k * 256 + lane * 4) = z;
    }
}

// ---------------- grouped GEMM: 256x256, 8 waves, 8-phase counted-vmcnt -------
// Tile T (even) in buffer 0, T+1 in buffer 1.  TWO B register sets (blo=cols
// 0-1, bhi=cols 2-3) so every LDS region is ds_read EXACTLY ONCE per K-tile:
//   P1: rdA(reg0)+rdBlo  -> mma(0,0)      B regions final-read end-P2
//   P2: rdBhi            -> mma(0,2)      A regions final-read end-P3
//   P3: rdA(reg4)        -> mma(4,2)
//   P4: (no reads)       -> mma(4,0) from live blo   [r5 bug: this re-read B]
// Stage slots (1 half-tile = 2 global_load_lds per phase), each issued only
// after the barrier following its region's final read:
//   P1:A0(T+1) P2:A1(T+1) P3:B0(T+2) P4:B1(T+2) P5:A0(T+2) P6:A1(T+2)
//   P7:B0(T+3) P8:B1(T+3)
// vmcnt(4) at P4: 12 outstanding {prevP7,prevP8,P1..P4} -> retires exactly
// tile T+1's 8 loads (read at P5).  vmcnt(4) at P8: {P3..P8} -> retires tile
// T+2 (read at next P1).  Never drained to 0 mid-loop.
// MODE 1: H = gelu(A @ W^T + b1) -> bf16 Hout
// MODE 2: y[row] += wt * (A @ W^T + b2)   (KSPLIT=2: xcd&1 picks K half)
template <int K, int N, int MODE, int KSPLIT>
__global__ __launch_bounds__(512) void moe_gemm(
        const __bf16* __restrict__ A, const __bf16* __restrict__ W,
        const float* __restrict__ bias,
        const int* __restrict__ aoff, const int* __restrict__ tile_e,
        const int* __restrict__ row_pk, const float* __restrict__ wt_pk,
        unsigned short* __restrict__ Hout, float* __restrict__ Y) {
    __shared__ __align__(16) __bf16 As[2][256 * 64];
    __shared__ __align__(16) __bf16 Bs[2][256 * 64];

    constexpr int NBT  = N / 256;
    constexpr int NBX  = (KSPLIT == 1) ? NBT / 2 : NBT;
    constexpr int KSEG = K / KSPLIT;
    constexpr int NKT  = KSEG / 64;          // 16 (GEMM1) / 32 (GEMM2 split-K)

    const int id = blockIdx.x;
    const int xcd = id & 7, slot = id >> 3;
    const int tloc = slot / NBX, nbi = slot % NBX;
    const int t  = (xcd >> 1) * 17 + tloc;
    const int nb = (KSPLIT == 1) ? (xcd & 1) * NBX + nbi : nbi;
    const int ks = (KSPLIT == 1) ? 0 : (xcd & 1);

    if (t * 256 >= aoff[4]) return;
    const int e = tile_e[t * 2];
    const int tid = threadIdx.x;
    const int lane = tid & 63;
    const int wave = tid >> 6;
    const int wm = wave >> 2, wn = wave & 3;     // 2M x 4N wave grid
    const int lm = lane & 15, q = lane >> 4;

    // staging: 64 rows x 64 K per instruction (512 thr x 16B); row = tid>>3,
    // k-chunk slot tid&7, xor-swizzled by row&7.  LDS dest linear: tid*16B.
    const int srow = tid >> 3;
    const int schunk = ((tid & 7) ^ (srow & 7)) * 8;
    const __bf16* Ag = A + (size_t)(t * 256 + srow) * K + ks * KSEG + schunk;
    const __bf16* Bg = W + (size_t)e * N * K + (size_t)(nb * 256 + srow) * K + ks * KSEG + schunk;

    auto stA = [&](int tile, int half) {           // stage A half-tile (128 rows)
        __bf16* dl = &As[tile & 1][half * 8192] + (size_t)tid * 8;
        const __bf16* sg = Ag + (size_t)(half * 128) * K + (size_t)tile * 64;
        load_lds16(sg, dl);
        load_lds16(sg + (size_t)64 * K, dl + 4096);
    };
    auto stB = [&](int tile, int half) {
        __bf16* dl = &Bs[tile & 1][half * 8192] + (size_t)tid * 8;
        const __bf16* sg = Bg + (size_t)(half * 128) * K + (size_t)tile * 64;
        load_lds16(sg, dl);
        load_lds16(sg + (size_t)64 * K, dl + 4096);
    };

    f32x4 acc[8][4] = {};
    bf16x8 a[8], blo[4], bhi[4];

    auto rdA = [&](const __bf16* buf, int i0) {    // 4 row-frags x 2 kk
#pragma unroll
        for (int i = 0; i < 4; ++i) {
            const int r = wm * 128 + (i0 + i) * 16 + lm;
#pragma unroll
            for (int kk = 0; kk < 2; ++kk)
                a[i * 2 + kk] = *(const bf16x8*)(buf + r * 64 + (((kk * 4 + q) ^ (r & 7)) * 8));
        }
    };
    auto rdBlo = [&](const __bf16* buf) {          // cols 0-1
#pragma unroll
        for (int j = 0; j < 2; ++j) {
            const int r = wn * 64 + j * 16 + lm;
#pragma unroll
            for (int kk = 0; kk < 2; ++kk)
                blo[j * 2 + kk] = *(const bf16x8*)(buf + r * 64 + (((kk * 4 + q) ^ (r & 7)) * 8));
        }
    };
    auto rdBhi = [&](const __bf16* buf) {          // cols 2-3
#pragma unroll
        for (int j = 0; j < 2; ++j) {
            const int r = wn * 64 + (j + 2) * 16 + lm;
#pragma unroll
            for (int kk = 0; kk < 2; ++kk)
                bhi[j * 2 + kk] = *(const bf16x8*)(buf + r * 64 + (((kk * 4 + q) ^ (r & 7)) * 8));
        }
    };
    auto mma8lo = [&](int i0) {                    // quadrant (i0, cols 0-1)
        __builtin_amdgcn_s_setprio(1);
#pragma unroll
        for (int kk = 0; kk < 2; ++kk)
#pragma unroll
            for (int i = 0; i < 4; ++i)
#pragma unroll
                for (int j = 0; j < 2; ++j)
                    acc[i0 + i][j] = __builtin_amdgcn_mfma_f32_16x16x32_bf16(
                        a[i * 2 + kk], blo[j * 2 + kk], acc[i0 + i][j], 0, 0, 0);
        __builtin_amdgcn_s_setprio(0);
    };
    auto mma8hi = [&](int i0) {                    // quadrant (i0, cols 2-3)
        __builtin_amdgcn_s_setprio(1);
#pragma unroll
        for (int kk = 0; kk < 2; ++kk)
#pragma unroll
            for (int i = 0; i < 4; ++i)
#pragma unroll
                for (int j = 0; j < 2; ++j)
                    acc[i0 + i][j + 2] = __builtin_amdgcn_mfma_f32_16x16x32_bf16(
                        a[i * 2 + kk], bhi[j * 2 + kk], acc[i0 + i][j + 2], 0, 0, 0);
        __builtin_amdgcn_s_setprio(0);
    };

    // prologue: tile 0 fully (8 loads) + B of tile 1 (4 loads); retire tile 0.
    stA(0, 0); stA(0, 1); stB(0, 0); stB(0, 1);
    if (1 < NKT) { stB(1, 0); stB(1, 1); }
    asm volatile("s_waitcnt vmcnt(4)" ::: "memory");
    BARRIER();

#pragma unroll 1
    for (int T = 0; T < NKT; T += 2) {
        const __bf16* A0 = &As[0][0];
        const __bf16* B0 = &Bs[0][0];
        const __bf16* A1 = &As[1][0];
        const __bf16* B1 = &Bs[1][0];
        // ---- K-tile T (buffer 0) ----
        // P1
        rdA(A0, 0); rdBlo(B0);
        stA(T + 1, 0);
        BARRIER(); mma8lo(0); BARRIER();
        // P2
        rdBhi(B0);
        stA(T + 1, 1);
        BARRIER(); mma8hi(0); BARRIER();
        // P3
        rdA(A0, 4);
        if (T + 2 < NKT) stB(T + 2, 0);
        BARRIER(); mma8hi(4); BARRIER();
        // P4 (no LDS reads: cols 0-1 still live in blo)
        if (T + 2 < NKT) { stB(T + 2, 1); asm volatile("s_waitcnt vmcnt(4)" ::: "memory"); }
        else             { asm volatile("s_waitcnt vmcnt(0)" ::: "memory"); }
        BARRIER(); mma8lo(4); BARRIER();
        // ---- K-tile T+1 (buffer 1) ----
        // P5
        rdA(A1, 0); rdBlo(B1);
        if (T + 2 < NKT) stA(T + 2, 0);
        BARRIER(); mma8lo(0); BARRIER();
        // P6
        rdBhi(B1);
        if (T + 2 < NKT) stA(T + 2, 1);
        BARRIER(); mma8hi(0); BARRIER();
        // P7
        rdA(A1, 4);
        if (T + 3 < NKT) stB(T + 3, 0);
        BARRIER(); mma8hi(4); BARRIER();
        // P8 (no LDS reads)
        if (T + 3 < NKT) { stB(T + 3, 1); asm volatile("s_waitcnt vmcnt(4)" ::: "memory"); }
        else             { asm volatile("s_waitcnt vmcnt(0)" ::: "memory"); }
        BARRIER(); mma8lo(4); BARRIER();
    }

    if (MODE == 1) {
#pragma unroll
        for (int j = 0; j < 4; ++j) {
            const int col = nb * 256 + wn * 64 + j * 16 + lm;
            const float bv = bias[e * N + col];
#pragma unroll
            for (int i = 0; i < 8; ++i) {
                const int rl = wm * 128 + i * 16 + q * 4;
                const size_t base = (size_t)(t * 256 + rl) * N + col;
#pragma unroll
                for (int r = 0; r < 4; ++r) {
                    float v = acc[i][j][r] + bv;
                    float u2 = 2.0f * v * (0.7978845608f + 0.0356774081f * v * v);
                    float g = v / (1.0f + __expf(-u2));
                    Hout[base + (size_t)r * N] = f2bf(g);
                }
            }
        }
    } else {
        float bv[4];
#pragma unroll
        for (int j = 0; j < 4; ++j)
            bv[j] = (ks == 0) ? bias[e * N + nb * 256 + wn * 64 + j * 16 + lm] : 0.f;
#pragma unroll
        for (int i = 0; i < 8; ++i) {
#pragma unroll
            for (int r = 0; r < 4; ++r) {
                const int ig = t * 256 + wm * 128 + i * 16 + q * 4 + r;
                const int brw = row_pk[ig];
                if (brw >= 0) {
                    const float wgt = wt_pk[ig];
#pragma unroll
                    for (int j = 0; j < 4; ++j) {
                        const int col = nb * 256 + wn * 64 + j * 16 + lm;
                        atomicAdd(Y + (size_t)brw * DD + col, (acc[i][j][r] + bv[j]) * wgt);
                    }
                }
            }
        }
    }
}

// ---------------- launch ----------------
extern "C" void kernel_launch(void* const* d_in, const int* in_sizes, int n_in,
                              void* d_out, int out_size, void* d_ws, size_t ws_size,
                              hipStream_t stream) {
    const float* x   = (const float*)d_in[0];
    const float* gw  = (const float*)d_in[1];
    const float* gb  = (const float*)d_in[2];
    const float* lnw = (const float*)d_in[3];
    const float* lnb = (const float*)d_in[4];
    const float* w1  = (const float*)d_in[5];
    const float* b1  = (const float*)d_in[6];
    const float* w2  = (const float*)d_in[7];
    const float* b2  = (const float*)d_in[8];
    float* out = (float*)d_out;

    char* ws = (char*)d_ws;
    size_t o = 0;
    auto alloc = [&](size_t bytes) { size_t r = o; o += (bytes + 255) & ~(size_t)255; return r; };
    float* mu       = (float*)(ws + alloc((size_t)BB * 4));
    float* rstd     = (float*)(ws + alloc((size_t)BB * 4));
    int*   cnt      = (int*)(ws + alloc(16));
    float* psum     = (float*)(ws + alloc(16));
    int*   done     = (int*)(ws + alloc(16));
    int*   aoff     = (int*)(ws + alloc(5 * 4));
    int*   te       = (int*)(ws + alloc(NT * 4));
    int*   rows_tmp = (int*)(ws + alloc((size_t)EE * BB * 4));
    float* wts_tmp  = (float*)(ws + alloc((size_t)EE * BB * 4));
    int*   row_pk   = (int*)(ws + alloc((size_t)CAP * 4));
    float* wt_pk    = (float*)(ws + alloc((size_t)CAP * 4));
    unsigned short* w1t = (unsigned short*)(ws + alloc((size_t)EE * DD * HH * 2));
    unsigned short* w2t = (unsigned short*)(ws + alloc((size_t)EE * DD * HH * 2));
    unsigned short* Apk = (unsigned short*)(ws + alloc((size_t)CAP * DD * 2));
    unsigned short* Hpk = (unsigned short*)(ws + alloc((size_t)CAP * HH * 2));
    if (o > ws_size) return;  // workspace insufficient: fail loudly

    float* y_out     = out;
    float* probs_out = out + (size_t)BB * DD;
    float* idx_out   = probs_out + (size_t)BB * EE;
    float* w_out     = idx_out + (size_t)BB * 2;
    float* aux_out   = w_out + (size_t)BB * 2;

    k_prep<<<dim3(64, 16, 8), 256, 0, stream>>>(w1, w2, w1t, w2t, cnt, psum, done);
    k_gate<<<BB / 32, 256, 0, stream>>>(x, gw, gb, mu, rstd, cnt, psum, done,
                                        rows_tmp, wts_tmp, probs_out, idx_out, w_out,
                                        aoff, te, aux_out);
    k_pack<<<CAP / 4, 256, 0, stream>>>(x, lnw, lnb, mu, rstd, cnt, aoff, te,
                                        rows_tmp, wts_tmp, row_pk, wt_pk, Apk, y_out);
    // GEMM1: M=CAP, N=4096, K=1024 -> 68 x 8 x 8 = 1088 blocks
    moe_gemm<DD, HH, 1, 1><<<8 * 17 * (HH / 256 / 2), 512, 0, stream>>>(
        (const __bf16*)Apk, (const __bf16*)w1t, b1, aoff, te, nullptr, nullptr, Hpk, nullptr);
    // GEMM2: M=CAP, N=1024, K=4096, split-K=2 -> 68 x 4 x 2 = 544 blocks
    moe_gemm<HH, DD, 2, 2><<<8 * 17 * (DD / 256), 512, 0, stream>>>(
        (const __bf16*)Hpk, (const __bf16*)w2t, b2, aoff, te, row_pk, wt_pk, nullptr, y_out);
}

// Round 7
// 597.776 us; speedup vs baseline: 1.2536x; 1.2536x over previous
//
#include <hip/hip_runtime.h>
#include <hip/hip_bf16.h>
#include <math.h>

// ---------------- constants ----------------
#define BB 8192
#define DD 1024
#define HH 4096
#define EE 4
#define NT 132              // row tiles of 128 covering B*k + per-expert pad
#define CAP (NT * 128)      // 16896 packed-row capacity

typedef __attribute__((ext_vector_type(8))) __bf16 bf16x8;
typedef __attribute__((ext_vector_type(8))) unsigned short u16x8;
typedef __attribute__((ext_vector_type(4))) float f32x4;

__device__ __forceinline__ unsigned short f2bf(float f) {
    union { float f; unsigned u; } c; c.f = f;
    unsigned u = c.u;
    unsigned r = (u + 0x7FFFu + ((u >> 16) & 1u)) >> 16;
    return (unsigned short)r;
}

__device__ __forceinline__ float bf2f(unsigned short u) {
    union { unsigned u; float f; } c; c.u = (unsigned)u << 16;
    return c.f;
}

__device__ __forceinline__ void load_lds16(const void* g, void* l) {
    __builtin_amdgcn_global_load_lds(
        (const __attribute__((address_space(1))) void*)g,
        (__attribute__((address_space(3))) void*)l, 16, 0, 0);
}

// ---------------- weight transpose + bf16 convert (both weights, one launch) ----
// z<4:  w1 [e][D][H] -> w1t [e][H][D]      (R=D, C=H)
// z>=4: w2 [e][H][D] -> w2t [e][D][H]      (R=H, C=D), grid remapped bijectively
// block (0,0,0) additionally zeroes the control vars for the fused gate/aux.
__global__ void k_prep(const float* __restrict__ w1, const float* __restrict__ w2,
                       unsigned short* __restrict__ w1t, unsigned short* __restrict__ w2t,
                       int* __restrict__ cnt, float* __restrict__ psum,
                       int* __restrict__ done) {
    __shared__ unsigned short tileT[64 * 72];   // [c][r], pad 72
    const int tid = threadIdx.x;
    if (blockIdx.x == 0 && blockIdx.y == 0 && blockIdx.z == 0) {
        if (tid < 4) cnt[tid] = 0;
        else if (tid < 8) psum[tid - 4] = 0.f;
        else if (tid == 8) done[0] = 0;
    }
    const int z = blockIdx.z;
    const float* s;
    unsigned short* d;
    int R, C, r0, c0;
    if (z < 4) {
        s = w1 + (size_t)z * DD * HH;  d = w1t + (size_t)z * DD * HH;
        R = DD; C = HH;
        r0 = blockIdx.y * 64; c0 = blockIdx.x * 64;
    } else {
        const int e = z - 4;
        s = w2 + (size_t)e * DD * HH;  d = w2t + (size_t)e * DD * HH;
        R = HH; C = DD;
        const int idx = blockIdx.y * 64 + blockIdx.x;   // 0..1023
        c0 = (idx & 15) * 64; r0 = (idx >> 4) * 64;
    }
    const int cc = (tid & 15) * 4;
#pragma unroll
    for (int it = 0; it < 4; ++it) {
        int rr = (tid >> 4) + it * 16;
        float4 v = *(const float4*)(s + (size_t)(r0 + rr) * C + c0 + cc);
        tileT[(cc + 0) * 72 + rr] = f2bf(v.x);
        tileT[(cc + 1) * 72 + rr] = f2bf(v.y);
        tileT[(cc + 2) * 72 + rr] = f2bf(v.z);
        tileT[(cc + 3) * 72 + rr] = f2bf(v.w);
    }
    __syncthreads();
#pragma unroll
    for (int it = 0; it < 2; ++it) {
        int chunk = tid + it * 256;
        int cl = chunk >> 3, rl = (chunk & 7) * 8;
        uint4 vv = *(const uint4*)&tileT[cl * 72 + rl];
        *(uint4*)(d + (size_t)(c0 + cl) * R + r0 + rl) = vv;
    }
}

// ---------------- gating + fused aux/offsets: wave-per-row, block routing ------
// rows_tmp packs (row<<1)|slot == blockIdx.x*64 + tid  (slot: 0=top1, 1=top2)
__global__ __launch_bounds__(256) void k_gate(
        const float* __restrict__ x, const float* __restrict__ gw,
        const float* __restrict__ gb,
        float* __restrict__ mu, float* __restrict__ rstd,
        int* __restrict__ cnt, float* __restrict__ psum, int* __restrict__ done,
        int* __restrict__ rows_tmp,
        float* __restrict__ probs_out, float* __restrict__ idx_out,
        float* __restrict__ w_out,
        int* __restrict__ aoff, int* __restrict__ tile_e,
        float* __restrict__ aux_out) {
    const int tid = threadIdx.x;
    const int lane = tid & 63, wv = tid >> 6;
    __shared__ int   s_e[64];
    __shared__ int   s_pos[64];
    __shared__ int   s_base[4];
    __shared__ float s_ps[4][4];
    __shared__ int   s_last;

    float lp0 = 0.f, lp1 = 0.f, lp2 = 0.f, lp3 = 0.f;

    for (int i = 0; i < 8; ++i) {
        const int rloc = wv * 8 + i;
        const int r = blockIdx.x * 32 + rloc;
        float l0 = 0, l1 = 0, l2 = 0, l3 = 0, s = 0, ss = 0;
#pragma unroll
        for (int k = 0; k < 4; ++k) {
            const int off = k * 256 + lane * 4;
            float4 xv = *(const float4*)(x + (size_t)r * DD + off);
            s  += xv.x + xv.y + xv.z + xv.w;
            ss += xv.x * xv.x + xv.y * xv.y + xv.z * xv.z + xv.w * xv.w;
            float4 g0 = *(const float4*)(gw + 0 * DD + off);
            float4 g1 = *(const float4*)(gw + 1 * DD + off);
            float4 g2 = *(const float4*)(gw + 2 * DD + off);
            float4 g3 = *(const float4*)(gw + 3 * DD + off);
            l0 += xv.x * g0.x + xv.y * g0.y + xv.z * g0.z + xv.w * g0.w;
            l1 += xv.x * g1.x + xv.y * g1.y + xv.z * g1.z + xv.w * g1.w;
            l2 += xv.x * g2.x + xv.y * g2.y + xv.z * g2.z + xv.w * g2.w;
            l3 += xv.x * g3.x + xv.y * g3.y + xv.z * g3.z + xv.w * g3.w;
        }
#pragma unroll
        for (int off = 32; off > 0; off >>= 1) {
            l0 += __shfl_xor(l0, off, 64);
            l1 += __shfl_xor(l1, off, 64);
            l2 += __shfl_xor(l2, off, 64);
            l3 += __shfl_xor(l3, off, 64);
            s  += __shfl_xor(s,  off, 64);
            ss += __shfl_xor(ss, off, 64);
        }
        if (lane == 0) {
            float m = s * (1.0f / DD);
            float var = ss * (1.0f / DD) - m * m;
            mu[r] = m;
            rstd[r] = rsqrtf(var + 1e-5f);
            float lg[4] = { l0 + gb[0], l1 + gb[1], l2 + gb[2], l3 + gb[3] };
            float mx = fmaxf(fmaxf(lg[0], lg[1]), fmaxf(lg[2], lg[3]));
            float p[4], tot = 0.f;
#pragma unroll
            for (int e = 0; e < 4; ++e) { p[e] = __expf(lg[e] - mx); tot += p[e]; }
            float inv = 1.0f / tot;
#pragma unroll
            for (int e = 0; e < 4; ++e) { p[e] *= inv; probs_out[(size_t)r * 4 + e] = p[e]; }
            lp0 += p[0]; lp1 += p[1]; lp2 += p[2]; lp3 += p[3];
            int e0 = 0; float p0 = p[0];
#pragma unroll
            for (int e = 1; e < 4; ++e) if (p[e] > p0) { p0 = p[e]; e0 = e; }
            int e1 = -1; float p1 = -1.f;
#pragma unroll
            for (int e = 0; e < 4; ++e) if (e != e0 && p[e] > p1) { p1 = p[e]; e1 = e; }
            float s2 = 1.0f / (p0 + p1 + 1e-9f);
            float w0 = p0 * s2, w1v = p1 * s2;
            idx_out[r * 2 + 0] = (float)e0;
            idx_out[r * 2 + 1] = (float)e1;
            w_out[r * 2 + 0] = w0;
            w_out[r * 2 + 1] = w1v;
            s_e[rloc * 2 + 0] = e0;
            s_e[rloc * 2 + 1] = e1;
        }
    }
    if (lane == 0) {
        s_ps[wv][0] = lp0; s_ps[wv][1] = lp1; s_ps[wv][2] = lp2; s_ps[wv][3] = lp3;
    }
    __syncthreads();
    if (tid < 4) {                      // block-local count + position assign
        int c = 0;
        for (int k = 0; k < 64; ++k)
            if (s_e[k] == tid) s_pos[k] = c++;
        s_base[tid] = atomicAdd(cnt + tid, c);
        atomicAdd(psum + tid, s_ps[0][tid] + s_ps[1][tid] + s_ps[2][tid] + s_ps[3][tid]);
    }
    __syncthreads();
    if (tid < 64) {
        int e = s_e[tid];
        int p = s_base[e] + s_pos[tid];
        rows_tmp[e * BB + p] = blockIdx.x * 64 + tid;   // == (row<<1)|slot
    }
    // ---- fused aux tail: last block computes aux loss, aoff, tile table ----
    __threadfence();
    __syncthreads();
    if (tid == 0) s_last = atomicAdd(done, 1);
    __syncthreads();
    if (s_last == (int)gridDim.x - 1 && tid == 0) {
        int c[4];
        for (int e = 0; e < 4; ++e) c[e] = atomicAdd(cnt + e, 0);
        float aux = 0.f;
        int a = 0; aoff[0] = 0;
        for (int e = 0; e < 4; ++e) {
            float mean_p = atomicAdd(psum + e, 0.f) * (1.0f / BB);
            aux += ((float)c[e] * (1.0f / (BB * 2))) * mean_p;
            a += ((c[e] + 127) >> 7) << 7; aoff[e + 1] = a;   // 128-aligned segments
        }
        aux_out[0] = 4.0f * aux;
        for (int t = 0; t < NT; ++t) {
            int ee = 0;
            for (int e = 0; e < 4; ++e)
                if (t * 128 >= aoff[e] && t * 128 < aoff[e + 1]) ee = e;
            tile_e[t] = ee;
        }
    }
}

// ---------------- pack: gather rows, LN + affine, bf16; build inverse pos map --
// 4 packed rows per block (wave-per-row).  pos[row*2+slot] = packed index, read
// by k_combine after GEMM2 (replaces the atomicAdd scatter epilogue).
__global__ __launch_bounds__(256) void k_pack(
        const float* __restrict__ x, const float* __restrict__ lnw,
        const float* __restrict__ lnb,
        const float* __restrict__ mu, const float* __restrict__ rstd,
        const int* __restrict__ cnt, const int* __restrict__ aoff,
        const int* __restrict__ tile_e,
        const int* __restrict__ rows_tmp,
        int* __restrict__ pos, unsigned short* __restrict__ Apk) {
    const int blk = blockIdx.x, tid = threadIdx.x;
    const int wv = tid >> 6, lane = tid & 63;
    const int i = blk * 4 + wv;
    if (i >= aoff[4]) return;
    const int e = tile_e[i >> 7];
    const int j = i - aoff[e];
    unsigned short* dst = Apk + (size_t)i * DD;
    if (j < cnt[e]) {
        const int v = rows_tmp[e * BB + j];   // (row<<1)|slot
        const int b = v >> 1;
        if (lane == 0) pos[v] = i;
        float m = mu[b], rs = rstd[b];
#pragma unroll
        for (int k = 0; k < 4; ++k) {
            const int off = k * 256 + lane * 4;
            float4 xv = *(const float4*)(x + (size_t)b * DD + off);
            float4 wv4 = *(const float4*)(lnw + (size_t)e * DD + off);
            float4 bv4 = *(const float4*)(lnb + (size_t)e * DD + off);
            ushort4 o;
            o.x = f2bf((xv.x - m) * rs * wv4.x + bv4.x);
            o.y = f2bf((xv.y - m) * rs * wv4.y + bv4.y);
            o.z = f2bf((xv.z - m) * rs * wv4.z + bv4.z);
            o.w = f2bf((xv.w - m) * rs * wv4.w + bv4.w);
            *(ushort4*)(dst + off) = o;
        }
    } else {
        ushort4 z; z.x = z.y = z.z = z.w = 0;
#pragma unroll
        for (int k = 0; k < 4; ++k) *(ushort4*)(dst + k * 256 + lane * 4) = z;
    }
}

// ---------------- grouped GEMM (round-0 m97 recipe, BK=64, XCD-aware raster) --
// [8-phase 256^2 line closed: 3 schedule variants all 296-316us @ 18.5-19.5%
//  MfmaUtil vs this structure's 217us @ 27% -- lockstep 8-wave barriers at
//  1 block/CU serialize LDS-read and MFMA instead of overlapping them.]
// MODE 1: Hout = gelu(A @ W^T + b1) as bf16     (K=1024, N=4096)
// MODE 2: Hout = (A @ W^T + b2) as bf16         (K=4096, N=1024) -- no atomics;
//         per-packed-row result, weighted gather happens in k_combine.
template <int K, int N, int MODE>
__global__ void moe_gemm(const __bf16* __restrict__ A, const __bf16* __restrict__ W,
                         const float* __restrict__ bias,
                         const int* __restrict__ aoff, const int* __restrict__ tile_e,
                         unsigned short* __restrict__ Hout) {
    __shared__ __align__(16) __bf16 As[128 * 64];
    __shared__ __align__(16) __bf16 Bs[128 * 64];

    constexpr int NBHALF = N / 128 / 2;                 // nb per XCD half
    constexpr int NBGRP  = (NBHALF >= 8) ? 8 : NBHALF;  // L2-resident B group
    const int id = blockIdx.x;
    const int xcd = id & 7, slot = id >> 3;
    const int nbg  = slot / (33 * NBGRP);
    const int rem  = slot - nbg * (33 * NBGRP);
    const int tloc = rem / NBGRP;
    const int nbi  = rem - tloc * NBGRP;
    const int t  = (xcd >> 1) * 33 + tloc;
    const int nb = (xcd & 1) * NBHALF + nbg * NBGRP + nbi;

    if (t * 128 >= aoff[4]) return;
    const int e = tile_e[t];
    const int tid = threadIdx.x;
    const int lane = tid & 63;
    const int wave = tid >> 6;
    const int wm = wave & 1, wn = wave >> 1;
    const int lm = lane & 15, q = lane >> 4;

    const int srow = tid >> 3;
    const int schunk = ((tid & 7) ^ (srow & 7)) * 8;
    const __bf16* Ag = A + (size_t)(t * 128 + srow) * K + schunk;
    const __bf16* Bg = W + (size_t)e * N * K + (size_t)(nb * 128 + srow) * K + schunk;
    __bf16* Al = As + tid * 8;
    __bf16* Bl = Bs + tid * 8;

    f32x4 acc[4][4] = {};
    int arow[4], brow[4];
#pragma unroll
    for (int i = 0; i < 4; ++i) {
        arow[i] = wm * 64 + i * 16 + lm;
        brow[i] = wn * 64 + i * 16 + lm;
    }

    for (int kt = 0; kt < K / 64; ++kt) {
#pragma unroll
        for (int i = 0; i < 4; ++i) load_lds16(Ag + (size_t)i * 32 * K + kt * 64, Al + i * 2048);
#pragma unroll
        for (int i = 0; i < 4; ++i) load_lds16(Bg + (size_t)i * 32 * K + kt * 64, Bl + i * 2048);
        __syncthreads();
#pragma unroll
        for (int kk = 0; kk < 2; ++kk) {
            bf16x8 af[4], bfr[4];
#pragma unroll
            for (int i = 0; i < 4; ++i)
                af[i] = *(const bf16x8*)(As + arow[i] * 64 + (((kk * 4 + q) ^ (arow[i] & 7)) * 8));
#pragma unroll
            for (int j = 0; j < 4; ++j)
                bfr[j] = *(const bf16x8*)(Bs + brow[j] * 64 + (((kk * 4 + q) ^ (brow[j] & 7)) * 8));
#pragma unroll
            for (int i = 0; i < 4; ++i)
#pragma unroll
                for (int j = 0; j < 4; ++j)
                    acc[i][j] = __builtin_amdgcn_mfma_f32_16x16x32_bf16(af[i], bfr[j], acc[i][j], 0, 0, 0);
        }
        __syncthreads();
    }

#pragma unroll
    for (int j = 0; j < 4; ++j) {
        int col = nb * 128 + wn * 64 + j * 16 + lm;
        float bv = bias[e * N + col];
#pragma unroll
        for (int i = 0; i < 4; ++i) {
            int rl = wm * 64 + i * 16 + q * 4;
            size_t base = (size_t)(t * 128 + rl) * N + col;
#pragma unroll
            for (int r = 0; r < 4; ++r) {
                float v = acc[i][j][r] + bv;
                if (MODE == 1) {
                    // tanh-form GELU via sigmoid: v * sigmoid(2u)
                    float u2 = 2.0f * v * (0.7978845608f + 0.0356774081f * v * v);
                    v = v / (1.0f + __expf(-u2));
                }
                Hout[base + (size_t)r * N] = f2bf(v);
            }
        }
    }
}

// ---------------- combine: y[b] = w0*Ypk[pos0] + w1*Ypk[pos1] ------------------
// Wave per row; replaces 17M atomicAdds + 32MB y-zeroing with a streamed gather.
__global__ __launch_bounds__(256) void k_combine(
        const unsigned short* __restrict__ Ypk, const int* __restrict__ pos,
        const float* __restrict__ w_out, float* __restrict__ y) {
    const int tid = threadIdx.x;
    const int wv = tid >> 6, lane = tid & 63;
    const int b = blockIdx.x * 4 + wv;
    int p0 = pos[b * 2 + 0], p1 = pos[b * 2 + 1];
    p0 = (p0 < 0) ? 0 : (p0 >= CAP ? CAP - 1 : p0);   // OOB insurance
    p1 = (p1 < 0) ? 0 : (p1 >= CAP ? CAP - 1 : p1);
    const float w0 = w_out[b * 2 + 0], w1 = w_out[b * 2 + 1];
    const unsigned short* r0 = Ypk + (size_t)p0 * DD;
    const unsigned short* r1 = Ypk + (size_t)p1 * DD;
    float* yr = y + (size_t)b * DD;
#pragma unroll
    for (int k = 0; k < 2; ++k) {
        const int off = k * 512 + lane * 8;
        u16x8 a = *(const u16x8*)(r0 + off);
        u16x8 c = *(const u16x8*)(r1 + off);
        float4 o0, o1;
        o0.x = w0 * bf2f(a[0]) + w1 * bf2f(c[0]);
        o0.y = w0 * bf2f(a[1]) + w1 * bf2f(c[1]);
        o0.z = w0 * bf2f(a[2]) + w1 * bf2f(c[2]);
        o0.w = w0 * bf2f(a[3]) + w1 * bf2f(c[3]);
        o1.x = w0 * bf2f(a[4]) + w1 * bf2f(c[4]);
        o1.y = w0 * bf2f(a[5]) + w1 * bf2f(c[5]);
        o1.z = w0 * bf2f(a[6]) + w1 * bf2f(c[6]);
        o1.w = w0 * bf2f(a[7]) + w1 * bf2f(c[7]);
        *(float4*)(yr + off)     = o0;
        *(float4*)(yr + off + 4) = o1;
    }
}

// ---------------- launch ----------------
extern "C" void kernel_launch(void* const* d_in, const int* in_sizes, int n_in,
                              void* d_out, int out_size, void* d_ws, size_t ws_size,
                              hipStream_t stream) {
    const float* x   = (const float*)d_in[0];
    const float* gw  = (const float*)d_in[1];
    const float* gb  = (const float*)d_in[2];
    const float* lnw = (const float*)d_in[3];
    const float* lnb = (const float*)d_in[4];
    const float* w1  = (const float*)d_in[5];
    const float* b1  = (const float*)d_in[6];
    const float* w2  = (const float*)d_in[7];
    const float* b2  = (const float*)d_in[8];
    float* out = (float*)d_out;

    char* ws = (char*)d_ws;
    size_t o = 0;
    auto alloc = [&](size_t bytes) { size_t r = o; o += (bytes + 255) & ~(size_t)255; return r; };
    float* mu       = (float*)(ws + alloc((size_t)BB * 4));
    float* rstd     = (float*)(ws + alloc((size_t)BB * 4));
    int*   cnt      = (int*)(ws + alloc(16));
    float* psum     = (float*)(ws + alloc(16));
    int*   done     = (int*)(ws + alloc(16));
    int*   aoff     = (int*)(ws + alloc(5 * 4));
    int*   te       = (int*)(ws + alloc(NT * 4));
    int*   rows_tmp = (int*)(ws + alloc((size_t)EE * BB * 4));
    int*   pos      = (int*)(ws + alloc((size_t)BB * 2 * 4));
    unsigned short* w1t = (unsigned short*)(ws + alloc((size_t)EE * DD * HH * 2));
    unsigned short* w2t = (unsigned short*)(ws + alloc((size_t)EE * DD * HH * 2));
    unsigned short* Apk = (unsigned short*)(ws + alloc((size_t)CAP * DD * 2));
    unsigned short* Hpk = (unsigned short*)(ws + alloc((size_t)CAP * HH * 2));
    unsigned short* Ypk = Apk;   // Apk is dead after GEMM1 reads it; GEMM2 reuses it
    if (o > ws_size) return;  // workspace insufficient: fail loudly

    float* y_out     = out;
    float* probs_out = out + (size_t)BB * DD;
    float* idx_out   = probs_out + (size_t)BB * EE;
    float* w_out     = idx_out + (size_t)BB * 2;
    float* aux_out   = w_out + (size_t)BB * 2;

    // 6 dispatches; no memsets (cnt/psum/done zeroed in k_prep; y fully
    // overwritten by k_combine -- no zeroing needed anywhere)
    k_prep<<<dim3(64, 16, 8), 256, 0, stream>>>(w1, w2, w1t, w2t, cnt, psum, done);
    k_gate<<<BB / 32, 256, 0, stream>>>(x, gw, gb, mu, rstd, cnt, psum, done,
                                        rows_tmp, probs_out, idx_out, w_out,
                                        aoff, te, aux_out);
    k_pack<<<CAP / 4, 256, 0, stream>>>(x, lnw, lnb, mu, rstd, cnt, aoff, te,
                                        rows_tmp, pos, Apk);
    moe_gemm<DD, HH, 1><<<8 * 33 * (HH / 256), 256, 0, stream>>>(
        (const __bf16*)Apk, (const __bf16*)w1t, b1, aoff, te, Hpk);
    moe_gemm<HH, DD, 2><<<8 * 33 * (DD / 256), 256, 0, stream>>>(
        (const __bf16*)Hpk, (const __bf16*)w2t, b2, aoff, te, Ypk);
    k_combine<<<BB / 4, 256, 0, stream>>>(Ypk, pos, w_out, y_out);
}

// Round 8
// 569.266 us; speedup vs baseline: 1.3164x; 1.0501x over previous
//
#include <hip/hip_runtime.h>
#include <hip/hip_bf16.h>
#include <math.h>

// ---------------- constants ----------------
#define BB 8192
#define DD 1024
#define HH 4096
#define EE 4
#define NT 132              // row tiles of 128 covering B*k + per-expert pad
#define CAP (NT * 128)      // 16896 packed-row capacity
#define GATE_BLKS 256       // gate: 32 rows/block
#define PREP_BLKS 8192      // prep: 8 z-slices x 1024 64x64 tiles

typedef __attribute__((ext_vector_type(8))) __bf16 bf16x8;
typedef __attribute__((ext_vector_type(8))) unsigned short u16x8;
typedef __attribute__((ext_vector_type(4))) float f32x4;

__device__ __forceinline__ unsigned short f2bf(float f) {
    union { float f; unsigned u; } c; c.f = f;
    unsigned u = c.u;
    unsigned r = (u + 0x7FFFu + ((u >> 16) & 1u)) >> 16;
    return (unsigned short)r;
}

__device__ __forceinline__ float bf2f(unsigned short u) {
    union { unsigned u; float f; } c; c.u = (unsigned)u << 16;
    return c.f;
}

__device__ __forceinline__ void load_lds16(const void* g, void* l) {
    __builtin_amdgcn_global_load_lds(
        (const __attribute__((address_space(1))) void*)g,
        (__attribute__((address_space(3))) void*)l, 16, 0, 0);
}

// ---------------- fused prep + gate (one dispatch; independent halves) ---------
// blocks [0, GATE_BLKS): gating/LN-stats/routing/aux  (verbatim round-7 k_gate;
//   1 block/CU alone -> its shuffle chains now hide under co-resident prep blocks)
// blocks [GATE_BLKS, GATE_BLKS+PREP_BLKS): weight transpose + bf16 convert
//   pb = blk - GATE_BLKS; z = pb>>10 (z<4: w1, z>=4: w2); idx = pb&1023.
// ctrl vars (cnt/psum/done) are zeroed by a preceding 768-B hipMemsetAsync.
__global__ __launch_bounds__(256) void k_pg(
        const float* __restrict__ w1, const float* __restrict__ w2,
        unsigned short* __restrict__ w1t, unsigned short* __restrict__ w2t,
        const float* __restrict__ x, const float* __restrict__ gw,
        const float* __restrict__ gb,
        float* __restrict__ mu, float* __restrict__ rstd,
        int* __restrict__ cnt, float* __restrict__ psum, int* __restrict__ done,
        int* __restrict__ rows_tmp,
        float* __restrict__ probs_out, float* __restrict__ idx_out,
        float* __restrict__ w_out,
        int* __restrict__ aoff, int* __restrict__ tile_e,
        float* __restrict__ aux_out) {
    __shared__ unsigned short tileT[64 * 72];   // prep: [c][r], pad 72
    __shared__ int   s_e[64];
    __shared__ int   s_pos[64];
    __shared__ int   s_base[4];
    __shared__ float s_ps[4][4];
    __shared__ int   s_last;
    const int tid = threadIdx.x;

    if (blockIdx.x >= GATE_BLKS) {
        // ======================= prep half =======================
        const int pb = (int)blockIdx.x - GATE_BLKS;
        const int z = pb >> 10;
        const int idx = pb & 1023;
        const float* s;
        unsigned short* d;
        int R, C, r0, c0;
        if (z < 4) {
            s = w1 + (size_t)z * DD * HH;  d = w1t + (size_t)z * DD * HH;
            R = DD; C = HH;
            r0 = (idx >> 6) * 64; c0 = (idx & 63) * 64;
        } else {
            const int e = z - 4;
            s = w2 + (size_t)e * DD * HH;  d = w2t + (size_t)e * DD * HH;
            R = HH; C = DD;
            c0 = (idx & 15) * 64; r0 = (idx >> 4) * 64;
        }
        const int cc = (tid & 15) * 4;
#pragma unroll
        for (int it = 0; it < 4; ++it) {
            int rr = (tid >> 4) + it * 16;
            float4 v = *(const float4*)(s + (size_t)(r0 + rr) * C + c0 + cc);
            tileT[(cc + 0) * 72 + rr] = f2bf(v.x);
            tileT[(cc + 1) * 72 + rr] = f2bf(v.y);
            tileT[(cc + 2) * 72 + rr] = f2bf(v.z);
            tileT[(cc + 3) * 72 + rr] = f2bf(v.w);
        }
        __syncthreads();
#pragma unroll
        for (int it = 0; it < 2; ++it) {
            int chunk = tid + it * 256;
            int cl = chunk >> 3, rl = (chunk & 7) * 8;
            uint4 vv = *(const uint4*)&tileT[cl * 72 + rl];
            *(uint4*)(d + (size_t)(c0 + cl) * R + r0 + rl) = vv;
        }
        return;
    }

    // ======================= gate half =======================
    const int gblk = blockIdx.x;
    const int lane = tid & 63, wv = tid >> 6;
    float lp0 = 0.f, lp1 = 0.f, lp2 = 0.f, lp3 = 0.f;

    for (int i = 0; i < 8; ++i) {
        const int rloc = wv * 8 + i;
        const int r = gblk * 32 + rloc;
        float l0 = 0, l1 = 0, l2 = 0, l3 = 0, s = 0, ss = 0;
#pragma unroll
        for (int k = 0; k < 4; ++k) {
            const int off = k * 256 + lane * 4;
            float4 xv = *(const float4*)(x + (size_t)r * DD + off);
            s  += xv.x + xv.y + xv.z + xv.w;
            ss += xv.x * xv.x + xv.y * xv.y + xv.z * xv.z + xv.w * xv.w;
            float4 g0 = *(const float4*)(gw + 0 * DD + off);
            float4 g1 = *(const float4*)(gw + 1 * DD + off);
            float4 g2 = *(const float4*)(gw + 2 * DD + off);
            float4 g3 = *(const float4*)(gw + 3 * DD + off);
            l0 += xv.x * g0.x + xv.y * g0.y + xv.z * g0.z + xv.w * g0.w;
            l1 += xv.x * g1.x + xv.y * g1.y + xv.z * g1.z + xv.w * g1.w;
            l2 += xv.x * g2.x + xv.y * g2.y + xv.z * g2.z + xv.w * g2.w;
            l3 += xv.x * g3.x + xv.y * g3.y + xv.z * g3.z + xv.w * g3.w;
        }
#pragma unroll
        for (int off = 32; off > 0; off >>= 1) {
            l0 += __shfl_xor(l0, off, 64);
            l1 += __shfl_xor(l1, off, 64);
            l2 += __shfl_xor(l2, off, 64);
            l3 += __shfl_xor(l3, off, 64);
            s  += __shfl_xor(s,  off, 64);
            ss += __shfl_xor(ss, off, 64);
        }
        if (lane == 0) {
            float m = s * (1.0f / DD);
            float var = ss * (1.0f / DD) - m * m;
            mu[r] = m;
            rstd[r] = rsqrtf(var + 1e-5f);
            float lg[4] = { l0 + gb[0], l1 + gb[1], l2 + gb[2], l3 + gb[3] };
            float mx = fmaxf(fmaxf(lg[0], lg[1]), fmaxf(lg[2], lg[3]));
            float p[4], tot = 0.f;
#pragma unroll
            for (int e = 0; e < 4; ++e) { p[e] = __expf(lg[e] - mx); tot += p[e]; }
            float inv = 1.0f / tot;
#pragma unroll
            for (int e = 0; e < 4; ++e) { p[e] *= inv; probs_out[(size_t)r * 4 + e] = p[e]; }
            lp0 += p[0]; lp1 += p[1]; lp2 += p[2]; lp3 += p[3];
            int e0 = 0; float p0 = p[0];
#pragma unroll
            for (int e = 1; e < 4; ++e) if (p[e] > p0) { p0 = p[e]; e0 = e; }
            int e1 = -1; float p1 = -1.f;
#pragma unroll
            for (int e = 0; e < 4; ++e) if (e != e0 && p[e] > p1) { p1 = p[e]; e1 = e; }
            float s2 = 1.0f / (p0 + p1 + 1e-9f);
            float w0 = p0 * s2, w1v = p1 * s2;
            idx_out[r * 2 + 0] = (float)e0;
            idx_out[r * 2 + 1] = (float)e1;
            w_out[r * 2 + 0] = w0;
            w_out[r * 2 + 1] = w1v;
            s_e[rloc * 2 + 0] = e0;
            s_e[rloc * 2 + 1] = e1;
        }
    }
    if (lane == 0) {
        s_ps[wv][0] = lp0; s_ps[wv][1] = lp1; s_ps[wv][2] = lp2; s_ps[wv][3] = lp3;
    }
    __syncthreads();
    if (tid < 4) {                      // block-local count + position assign
        int c = 0;
        for (int k = 0; k < 64; ++k)
            if (s_e[k] == tid) s_pos[k] = c++;
        s_base[tid] = atomicAdd(cnt + tid, c);
        atomicAdd(psum + tid, s_ps[0][tid] + s_ps[1][tid] + s_ps[2][tid] + s_ps[3][tid]);
    }
    __syncthreads();
    if (tid < 64) {
        int e = s_e[tid];
        int p = s_base[e] + s_pos[tid];
        rows_tmp[e * BB + p] = gblk * 64 + tid;   // == (row<<1)|slot
    }
    // ---- fused aux tail: last gate block computes aux loss, aoff, tile table --
    __threadfence();
    __syncthreads();
    if (tid == 0) s_last = atomicAdd(done, 1);
    __syncthreads();
    if (s_last == GATE_BLKS - 1 && tid == 0) {
        int c[4];
        for (int e = 0; e < 4; ++e) c[e] = atomicAdd(cnt + e, 0);
        float aux = 0.f;
        int a = 0; aoff[0] = 0;
        for (int e = 0; e < 4; ++e) {
            float mean_p = atomicAdd(psum + e, 0.f) * (1.0f / BB);
            aux += ((float)c[e] * (1.0f / (BB * 2))) * mean_p;
            a += ((c[e] + 127) >> 7) << 7; aoff[e + 1] = a;   // 128-aligned segments
        }
        aux_out[0] = 4.0f * aux;
        for (int t = 0; t < NT; ++t) {
            int ee = 0;
            for (int e = 0; e < 4; ++e)
                if (t * 128 >= aoff[e] && t * 128 < aoff[e + 1]) ee = e;
            tile_e[t] = ee;
        }
    }
}

// ---------------- pack: gather rows, LN + affine, bf16; build inverse pos map --
// 4 packed rows per block (wave-per-row).  pos[row*2+slot] = packed index, read
// by k_combine after GEMM2.
__global__ __launch_bounds__(256) void k_pack(
        const float* __restrict__ x, const float* __restrict__ lnw,
        const float* __restrict__ lnb,
        const float* __restrict__ mu, const float* __restrict__ rstd,
        const int* __restrict__ cnt, const int* __restrict__ aoff,
        const int* __restrict__ tile_e,
        const int* __restrict__ rows_tmp,
        int* __restrict__ pos, unsigned short* __restrict__ Apk) {
    const int blk = blockIdx.x, tid = threadIdx.x;
    const int wv = tid >> 6, lane = tid & 63;
    const int i = blk * 4 + wv;
    if (i >= aoff[4]) return;
    const int e = tile_e[i >> 7];
    const int j = i - aoff[e];
    unsigned short* dst = Apk + (size_t)i * DD;
    if (j < cnt[e]) {
        const int v = rows_tmp[e * BB + j];   // (row<<1)|slot
        const int b = v >> 1;
        if (lane == 0) pos[v] = i;
        float m = mu[b], rs = rstd[b];
#pragma unroll
        for (int k = 0; k < 4; ++k) {
            const int off = k * 256 + lane * 4;
            float4 xv = *(const float4*)(x + (size_t)b * DD + off);
            float4 wv4 = *(const float4*)(lnw + (size_t)e * DD + off);
            float4 bv4 = *(const float4*)(lnb + (size_t)e * DD + off);
            ushort4 o;
            o.x = f2bf((xv.x - m) * rs * wv4.x + bv4.x);
            o.y = f2bf((xv.y - m) * rs * wv4.y + bv4.y);
            o.z = f2bf((xv.z - m) * rs * wv4.z + bv4.z);
            o.w = f2bf((xv.w - m) * rs * wv4.w + bv4.w);
            *(ushort4*)(dst + off) = o;
        }
    } else {
        ushort4 z; z.x = z.y = z.z = z.w = 0;
#pragma unroll
        for (int k = 0; k < 4; ++k) *(ushort4*)(dst + k * 256 + lane * 4) = z;
    }
}

// ---------------- grouped GEMM (m97 recipe, BK=64, XCD-aware raster) ----------
// At the verified plain-HIP 128^2-structure ceiling (830 TF, MfmaUtil ~35%).
// [8-phase 256^2 line closed: 3 variants all 296-316us @ 18.5-19.5%.  Explicit
//  dbuf prefetch corpus-neutral (m99/m100).  MX-fp8 parked on precision risk.]
// MODE 1: Hout = gelu(A @ W^T + b1) as bf16     (K=1024, N=4096)
// MODE 2: Hout = (A @ W^T + b2) as bf16         (K=4096, N=1024); weighted
//         gather happens in k_combine (no atomics, no y zeroing).
template <int K, int N, int MODE>
__global__ void moe_gemm(const __bf16* __restrict__ A, const __bf16* __restrict__ W,
                         const float* __restrict__ bias,
                         const int* __restrict__ aoff, const int* __restrict__ tile_e,
                         unsigned short* __restrict__ Hout) {
    __shared__ __align__(16) __bf16 As[128 * 64];
    __shared__ __align__(16) __bf16 Bs[128 * 64];

    constexpr int NBHALF = N / 128 / 2;                 // nb per XCD half
    constexpr int NBGRP  = (NBHALF >= 8) ? 8 : NBHALF;  // L2-resident B group
    const int id = blockIdx.x;
    const int xcd = id & 7, slot = id >> 3;
    const int nbg  = slot / (33 * NBGRP);
    const int rem  = slot - nbg * (33 * NBGRP);
    const int tloc = rem / NBGRP;
    const int nbi  = rem - tloc * NBGRP;
    const int t  = (xcd >> 1) * 33 + tloc;
    const int nb = (xcd & 1) * NBHALF + nbg * NBGRP + nbi;

    if (t * 128 >= aoff[4]) return;
    const int e = tile_e[t];
    const int tid = threadIdx.x;
    const int lane = tid & 63;
    const int wave = tid >> 6;
    const int wm = wave & 1, wn = wave >> 1;
    const int lm = lane & 15, q = lane >> 4;

    const int srow = tid >> 3;
    const int schunk = ((tid & 7) ^ (srow & 7)) * 8;
    const __bf16* Ag = A + (size_t)(t * 128 + srow) * K + schunk;
    const __bf16* Bg = W + (size_t)e * N * K + (size_t)(nb * 128 + srow) * K + schunk;
    __bf16* Al = As + tid * 8;
    __bf16* Bl = Bs + tid * 8;

    f32x4 acc[4][4] = {};
    int arow[4], brow[4];
#pragma unroll
    for (int i = 0; i < 4; ++i) {
        arow[i] = wm * 64 + i * 16 + lm;
        brow[i] = wn * 64 + i * 16 + lm;
    }

    for (int kt = 0; kt < K / 64; ++kt) {
#pragma unroll
        for (int i = 0; i < 4; ++i) load_lds16(Ag + (size_t)i * 32 * K + kt * 64, Al + i * 2048);
#pragma unroll
        for (int i = 0; i < 4; ++i) load_lds16(Bg + (size_t)i * 32 * K + kt * 64, Bl + i * 2048);
        __syncthreads();
#pragma unroll
        for (int kk = 0; kk < 2; ++kk) {
            bf16x8 af[4], bfr[4];
#pragma unroll
            for (int i = 0; i < 4; ++i)
                af[i] = *(const bf16x8*)(As + arow[i] * 64 + (((kk * 4 + q) ^ (arow[i] & 7)) * 8));
#pragma unroll
            for (int j = 0; j < 4; ++j)
                bfr[j] = *(const bf16x8*)(Bs + brow[j] * 64 + (((kk * 4 + q) ^ (brow[j] & 7)) * 8));
#pragma unroll
            for (int i = 0; i < 4; ++i)
#pragma unroll
                for (int j = 0; j < 4; ++j)
                    acc[i][j] = __builtin_amdgcn_mfma_f32_16x16x32_bf16(af[i], bfr[j], acc[i][j], 0, 0, 0);
        }
        __syncthreads();
    }

#pragma unroll
    for (int j = 0; j < 4; ++j) {
        int col = nb * 128 + wn * 64 + j * 16 + lm;
        float bv = bias[e * N + col];
#pragma unroll
        for (int i = 0; i < 4; ++i) {
            int rl = wm * 64 + i * 16 + q * 4;
            size_t base = (size_t)(t * 128 + rl) * N + col;
#pragma unroll
            for (int r = 0; r < 4; ++r) {
                float v = acc[i][j][r] + bv;
                if (MODE == 1) {
                    // tanh-form GELU via sigmoid: v * sigmoid(2u)
                    float u2 = 2.0f * v * (0.7978845608f + 0.0356774081f * v * v);
                    v = v / (1.0f + __expf(-u2));
                }
                Hout[base + (size_t)r * N] = f2bf(v);
            }
        }
    }
}

// ---------------- combine: y[b] = w0*Ypk[pos0] + w1*Ypk[pos1] ------------------
__global__ __launch_bounds__(256) void k_combine(
        const unsigned short* __restrict__ Ypk, const int* __restrict__ pos,
        const float* __restrict__ w_out, float* __restrict__ y) {
    const int tid = threadIdx.x;
    const int wv = tid >> 6, lane = tid & 63;
    const int b = blockIdx.x * 4 + wv;
    int p0 = pos[b * 2 + 0], p1 = pos[b * 2 + 1];
    p0 = (p0 < 0) ? 0 : (p0 >= CAP ? CAP - 1 : p0);   // OOB insurance
    p1 = (p1 < 0) ? 0 : (p1 >= CAP ? CAP - 1 : p1);
    const float w0 = w_out[b * 2 + 0], w1 = w_out[b * 2 + 1];
    const unsigned short* r0 = Ypk + (size_t)p0 * DD;
    const unsigned short* r1 = Ypk + (size_t)p1 * DD;
    float* yr = y + (size_t)b * DD;
#pragma unroll
    for (int k = 0; k < 2; ++k) {
        const int off = k * 512 + lane * 8;
        u16x8 a = *(const u16x8*)(r0 + off);
        u16x8 c = *(const u16x8*)(r1 + off);
        float4 o0, o1;
        o0.x = w0 * bf2f(a[0]) + w1 * bf2f(c[0]);
        o0.y = w0 * bf2f(a[1]) + w1 * bf2f(c[1]);
        o0.z = w0 * bf2f(a[2]) + w1 * bf2f(c[2]);
        o0.w = w0 * bf2f(a[3]) + w1 * bf2f(c[3]);
        o1.x = w0 * bf2f(a[4]) + w1 * bf2f(c[4]);
        o1.y = w0 * bf2f(a[5]) + w1 * bf2f(c[5]);
        o1.z = w0 * bf2f(a[6]) + w1 * bf2f(c[6]);
        o1.w = w0 * bf2f(a[7]) + w1 * bf2f(c[7]);
        *(float4*)(yr + off)     = o0;
        *(float4*)(yr + off + 4) = o1;
    }
}

// ---------------- launch ----------------
extern "C" void kernel_launch(void* const* d_in, const int* in_sizes, int n_in,
                              void* d_out, int out_size, void* d_ws, size_t ws_size,
                              hipStream_t stream) {
    const float* x   = (const float*)d_in[0];
    const float* gw  = (const float*)d_in[1];
    const float* gb  = (const float*)d_in[2];
    const float* lnw = (const float*)d_in[3];
    const float* lnb = (const float*)d_in[4];
    const float* w1  = (const float*)d_in[5];
    const float* b1  = (const float*)d_in[6];
    const float* w2  = (const float*)d_in[7];
    const float* b2  = (const float*)d_in[8];
    float* out = (float*)d_out;

    char* ws = (char*)d_ws;
    size_t o = 0;
    auto alloc = [&](size_t bytes) { size_t r = o; o += (bytes + 255) & ~(size_t)255; return r; };
    float* mu       = (float*)(ws + alloc((size_t)BB * 4));
    float* rstd     = (float*)(ws + alloc((size_t)BB * 4));
    char*  ctrl     = ws + alloc(768);       // cnt | psum | done (256 B apart)
    int*   cnt      = (int*)ctrl;
    float* psum     = (float*)(ctrl + 256);
    int*   done     = (int*)(ctrl + 512);
    int*   aoff     = (int*)(ws + alloc(5 * 4));
    int*   te       = (int*)(ws + alloc(NT * 4));
    int*   rows_tmp = (int*)(ws + alloc((size_t)EE * BB * 4));
    int*   pos      = (int*)(ws + alloc((size_t)BB * 2 * 4));
    unsigned short* w1t = (unsigned short*)(ws + alloc((size_t)EE * DD * HH * 2));
    unsigned short* w2t = (unsigned short*)(ws + alloc((size_t)EE * DD * HH * 2));
    unsigned short* Apk = (unsigned short*)(ws + alloc((size_t)CAP * DD * 2));
    unsigned short* Hpk = (unsigned short*)(ws + alloc((size_t)CAP * HH * 2));
    unsigned short* Ypk = Apk;   // Apk dead after GEMM1 reads it; GEMM2 reuses it
    if (o > ws_size) return;  // workspace insufficient: fail loudly

    float* y_out     = out;
    float* probs_out = out + (size_t)BB * DD;
    float* idx_out   = probs_out + (size_t)BB * EE;
    float* w_out     = idx_out + (size_t)BB * 2;
    float* aux_out   = w_out + (size_t)BB * 2;

    // 5 kernel dispatches + 1 tiny memset; prep and gate co-resident in k_pg
    hipMemsetAsync(ctrl, 0, 768, stream);
    k_pg<<<GATE_BLKS + PREP_BLKS, 256, 0, stream>>>(
        w1, w2, w1t, w2t, x, gw, gb, mu, rstd, cnt, psum, done,
        rows_tmp, probs_out, idx_out, w_out, aoff, te, aux_out);
    k_pack<<<CAP / 4, 256, 0, stream>>>(x, lnw, lnb, mu, rstd, cnt, aoff, te,
                                        rows_tmp, pos, Apk);
    moe_gemm<DD, HH, 1><<<8 * 33 * (HH / 256), 256, 0, stream>>>(
        (const __bf16*)Apk, (const __bf16*)w1t, b1, aoff, te, Hpk);
    moe_gemm<HH, DD, 2><<<8 * 33 * (DD / 256), 256, 0, stream>>>(
        (const __bf16*)Hpk, (const __bf16*)w2t, b2, aoff, te, Ypk);
    k_combine<<<BB / 4, 256, 0, stream>>>(Ypk, pos, w_out, y_out);
}